// Round 1
// baseline (492.321 us; speedup 1.0000x reference)
//
#include <hip/hip_runtime.h>
#include <hip/hip_bf16.h>

#define B_ 16
#define N_ 2048
#define D_ 64

typedef __bf16 bf16x8 __attribute__((ext_vector_type(8)));
typedef __bf16 bf16x4 __attribute__((ext_vector_type(4)));
typedef __bf16 bf16x2 __attribute__((ext_vector_type(2)));
typedef float  f32x4  __attribute__((ext_vector_type(4)));
typedef float  f32x16 __attribute__((ext_vector_type(16)));

// load 8 bf16 from an 8B-aligned LDS address (rowstride 136B -> two b64 reads)
static __device__ __forceinline__ bf16x8 ld_frag(const __bf16* p) {
  bf16x4 lo = *(const bf16x4*)p;
  bf16x4 hi = *(const bf16x4*)(p + 4);
  return __builtin_shufflevector(lo, hi, 0, 1, 2, 3, 4, 5, 6, 7);
}

__global__ __launch_bounds__(256, 3)
void General_Attention_62251255988379_kernel(const float* __restrict__ Q,
                                             const float* __restrict__ K,
                                             const float* __restrict__ V,
                                             float* __restrict__ out) {
  // frag-layout LDS: Qs/Ks = [kchunk h 0..7][row 0..63][8 bf16] (16B units, conflict-free)
  __shared__ __bf16 QsL[4096];
  __shared__ __bf16 KsL[4096];
  __shared__ __bf16 VtL[4352];  // V^T col-major: [n 0..63][k 0..63], rowstride 68 elems (136B)
  __shared__ __bf16 PtL[4352];  // P: [wr*32+m][k 0..63], rowstride 68 elems
  __shared__ float  lsum[64];

  const int tid  = threadIdx.x;
  const int blk  = blockIdx.x;
  const int bb   = blk & 15;
  const int u    = blk >> 4;                    // heavy row-tiles dispatch first;
  const int rb   = (u < 16) ? (31 - u) : (u - 16);  // pair (c, c+256) sums to const work
  const int row0 = rb * 64;
  const int lane = tid & 63;
  const int wave = tid >> 6;
  const int wr   = wave & 1;    // row subtile
  const int wc   = wave >> 1;   // col subtile
  const int ln   = lane & 31;
  const int half = lane >> 5;

  const float* Qb = Q + (size_t)bb * N_ * D_;
  const float* Kb = K + (size_t)bb * N_ * D_;
  const float* Vb = V + (size_t)bb * N_ * D_;
  float* Ob = out + (size_t)bb * N_ * D_;
  float* Ab = out + (size_t)B_ * N_ * D_ + (size_t)bb * N_ * N_;

  if (tid < 64) lsum[tid] = 0.0f;

  // ---- stage Q tile once, pre-scaled by 1/sqrt(D)=0.125 (exact pow2) ----
  {
    const int m  = tid >> 2;
    const int c4 = tid & 3;
    const f32x4* src = (const f32x4*)(Qb + (size_t)(row0 + m) * D_ + c4 * 16);
    f32x4 f0 = src[0], f1 = src[1], f2 = src[2], f3 = src[3];
    bf16x8 w0, w1;
#pragma unroll
    for (int i = 0; i < 4; ++i) {
      w0[i]     = (__bf16)(f0[i] * 0.125f);
      w0[i + 4] = (__bf16)(f1[i] * 0.125f);
      w1[i]     = (__bf16)(f2[i] * 0.125f);
      w1[i + 4] = (__bf16)(f3[i] * 0.125f);
    }
    *(bf16x8*)&QsL[(2 * c4 + 0) * 512 + m * 8] = w0;
    *(bf16x8*)&QsL[(2 * c4 + 1) * 512 + m * 8] = w1;
  }
  __syncthreads();

  bf16x8 qf[4];
#pragma unroll
  for (int kk = 0; kk < 4; ++kk)
    qf[kk] = *(const bf16x8*)&QsL[(2 * kk + half) * 512 + (32 * wr + ln) * 8];

  // ===================== pass A: row sums of exp(s) =====================
  float sums[16];
#pragma unroll
  for (int r = 0; r < 16; ++r) sums[r] = 0.0f;

#pragma unroll 1
  for (int ct = 0; ct <= rb; ++ct) {
    const int c0 = ct * 64;
    {  // stage K tile -> bf16 frag layout
      const int n  = tid >> 2;
      const int c4 = tid & 3;
      const f32x4* src = (const f32x4*)(Kb + (size_t)(c0 + n) * D_ + c4 * 16);
      f32x4 f0 = src[0], f1 = src[1], f2 = src[2], f3 = src[3];
      bf16x8 w0, w1;
#pragma unroll
      for (int i = 0; i < 4; ++i) {
        w0[i] = (__bf16)f0[i]; w0[i + 4] = (__bf16)f1[i];
        w1[i] = (__bf16)f2[i]; w1[i + 4] = (__bf16)f3[i];
      }
      *(bf16x8*)&KsL[(2 * c4 + 0) * 512 + n * 8] = w0;
      *(bf16x8*)&KsL[(2 * c4 + 1) * 512 + n * 8] = w1;
    }
    __syncthreads();

    f32x16 s;
#pragma unroll
    for (int i = 0; i < 16; ++i) s[i] = 0.0f;
#pragma unroll
    for (int kk = 0; kk < 4; ++kk) {
      bf16x8 kf = *(const bf16x8*)&KsL[(2 * kk + half) * 512 + (32 * wc + ln) * 8];
      s = __builtin_amdgcn_mfma_f32_32x32x16_bf16(qf[kk], kf, s, 0, 0, 0);
    }
    const bool diag = (ct == rb);
#pragma unroll
    for (int r = 0; r < 16; ++r) {
      float e = __expf(s[r]);
      if (diag) {
        const int ro = (r & 3) + 8 * (r >> 2) + 4 * half;
        e = ((32 * wc + ln) <= (32 * wr + ro)) ? e : 0.0f;
      }
      sums[r] += e;
    }
    __syncthreads();
  }

  // butterfly-reduce across the 32 lanes holding each row's columns
#pragma unroll
  for (int r = 0; r < 16; ++r) {
    float v = sums[r];
    v += __shfl_xor(v, 1);
    v += __shfl_xor(v, 2);
    v += __shfl_xor(v, 4);
    v += __shfl_xor(v, 8);
    v += __shfl_xor(v, 16);
    sums[r] = v;
  }
  if (ln == 0) {  // lanes 0 and 32: one per half
#pragma unroll
    for (int r = 0; r < 16; ++r) {
      const int ro = (r & 3) + 8 * (r >> 2) + 4 * half;
      atomicAdd(&lsum[32 * wr + ro], sums[r]);
    }
  }
  __syncthreads();

  float linv[16];
#pragma unroll
  for (int r = 0; r < 16; ++r) {
    const int ro = (r & 3) + 8 * (r >> 2) + 4 * half;
    linv[r] = 1.0f / lsum[32 * wr + ro];
  }

  // ===================== pass B: att writes + O = P.V =====================
  f32x16 o0, o1;
#pragma unroll
  for (int i = 0; i < 16; ++i) { o0[i] = 0.0f; o1[i] = 0.0f; }

#pragma unroll 1
  for (int ct = 0; ct <= rb; ++ct) {
    const int c0 = ct * 64;
    {  // stage K tile (re-read; L2-resident)
      const int n  = tid >> 2;
      const int c4 = tid & 3;
      const f32x4* src = (const f32x4*)(Kb + (size_t)(c0 + n) * D_ + c4 * 16);
      f32x4 f0 = src[0], f1 = src[1], f2 = src[2], f3 = src[3];
      bf16x8 w0, w1;
#pragma unroll
      for (int i = 0; i < 4; ++i) {
        w0[i] = (__bf16)f0[i]; w0[i + 4] = (__bf16)f1[i];
        w1[i] = (__bf16)f2[i]; w1[i + 4] = (__bf16)f3[i];
      }
      *(bf16x8*)&KsL[(2 * c4 + 0) * 512 + n * 8] = w0;
      *(bf16x8*)&KsL[(2 * c4 + 1) * 512 + n * 8] = w1;
    }
    {  // stage V^T: pairs of rows -> packed b32 LDS writes
      const int g  = tid >> 4;           // 0..15
      const int n0 = (tid & 15) * 4;
#pragma unroll
      for (int p = 0; p < 2; ++p) {
        const int k = 2 * g + 32 * p;
        const f32x4 va = *(const f32x4*)(Vb + (size_t)(c0 + k) * D_ + n0);
        const f32x4 vb = *(const f32x4*)(Vb + (size_t)(c0 + k + 1) * D_ + n0);
#pragma unroll
        for (int i = 0; i < 4; ++i) {
          bf16x2 pr;
          pr[0] = (__bf16)va[i];
          pr[1] = (__bf16)vb[i];
          *(bf16x2*)&VtL[(n0 + i) * 68 + k] = pr;
        }
      }
    }
    __syncthreads();

    f32x16 s;
#pragma unroll
    for (int i = 0; i < 16; ++i) s[i] = 0.0f;
#pragma unroll
    for (int kk = 0; kk < 4; ++kk) {
      bf16x8 kf = *(const bf16x8*)&KsL[(2 * kk + half) * 512 + (32 * wc + ln) * 8];
      s = __builtin_amdgcn_mfma_f32_32x32x16_bf16(qf[kk], kf, s, 0, 0, 0);
    }
    const bool diag = (ct == rb);
#pragma unroll
    for (int r = 0; r < 16; ++r) {
      const int ro = (r & 3) + 8 * (r >> 2) + 4 * half;
      float e = __expf(s[r]);
      if (diag) e = ((32 * wc + ln) <= (32 * wr + ro)) ? e : 0.0f;
      const float pv = e * linv[r];
      __builtin_nontemporal_store(pv,
          Ab + (size_t)(row0 + 32 * wr + ro) * N_ + c0 + 32 * wc + ln);
      PtL[(wr * 32 + ro) * 68 + 32 * wc + ln] = (__bf16)pv;
    }
    __syncthreads();

    bf16x8 af[4];
#pragma unroll
    for (int kk = 0; kk < 4; ++kk)
      af[kk] = ld_frag(&PtL[(wr * 32 + ln) * 68 + 16 * kk + 8 * half]);
#pragma unroll
    for (int kk = 0; kk < 4; ++kk) {
      bf16x8 b0 = ld_frag(&VtL[ln * 68 + 16 * kk + 8 * half]);
      bf16x8 b1 = ld_frag(&VtL[(32 + ln) * 68 + 16 * kk + 8 * half]);
      o0 = __builtin_amdgcn_mfma_f32_32x32x16_bf16(af[kk], b0, o0, 0, 0, 0);
      o1 = __builtin_amdgcn_mfma_f32_32x32x16_bf16(af[kk], b1, o1, 0, 0, 0);
    }
    __syncthreads();
  }

  // ---- store O ----
#pragma unroll
  for (int r = 0; r < 16; ++r) {
    const int ro = (r & 3) + 8 * (r >> 2) + 4 * half;
    float* op = Ob + (size_t)(row0 + 32 * wr + ro) * D_;
    __builtin_nontemporal_store(o0[r], op + ln);
    __builtin_nontemporal_store(o1[r], op + 32 + ln);
  }

  // ---- zero-fill strictly-upper columns of att for this row tile ----
  const int cz0 = 64 * (rb + 1);
  if (cz0 < N_) {
    f32x4 z = {0.0f, 0.0f, 0.0f, 0.0f};
#pragma unroll 1
    for (int rr = (tid >> 6); rr < 64; rr += 4) {
      float* rowp = Ab + (size_t)(row0 + rr) * N_;
      for (int x = cz0 + (tid & 63) * 4; x < N_; x += 256)
        __builtin_nontemporal_store(z, (f32x4*)(rowp + x));
    }
  }
}

extern "C" void kernel_launch(void* const* d_in, const int* in_sizes, int n_in,
                              void* d_out, int out_size, void* d_ws, size_t ws_size,
                              hipStream_t stream) {
  const float* Q = (const float*)d_in[0];
  const float* K = (const float*)d_in[1];
  const float* V = (const float*)d_in[2];
  (void)in_sizes; (void)n_in; (void)out_size; (void)d_ws; (void)ws_size;
  float* out = (float*)d_out;
  General_Attention_62251255988379_kernel<<<dim3(512), dim3(256), 0, stream>>>(Q, K, V, out);
}

// Round 2
// 452.776 us; speedup vs baseline: 1.0873x; 1.0873x over previous
//
#include <hip/hip_runtime.h>
#include <hip/hip_bf16.h>

#define B_ 16
#define N_ 2048
#define D_ 64

typedef __bf16 bf16x8 __attribute__((ext_vector_type(8)));
typedef __bf16 bf16x4 __attribute__((ext_vector_type(4)));
typedef __bf16 bf16x2 __attribute__((ext_vector_type(2)));
typedef float  f32x4  __attribute__((ext_vector_type(4)));
typedef float  f32x16 __attribute__((ext_vector_type(16)));

// load 8 bf16 from an 8B-aligned LDS address (two b64 reads)
static __device__ __forceinline__ bf16x8 ld_frag(const __bf16* p) {
  bf16x4 lo = *(const bf16x4*)p;
  bf16x4 hi = *(const bf16x4*)(p + 4);
  return __builtin_shufflevector(lo, hi, 0, 1, 2, 3, 4, 5, 6, 7);
}

// convert 16 staged floats -> bf16 frag layout [kchunk][row][8]
static __device__ __forceinline__ void stage_K(__bf16* dst, int n, int c4,
                                               const f32x4* f) {
  bf16x8 w0, w1;
#pragma unroll
  for (int i = 0; i < 4; ++i) {
    w0[i] = (__bf16)f[0][i]; w0[i + 4] = (__bf16)f[1][i];
    w1[i] = (__bf16)f[2][i]; w1[i + 4] = (__bf16)f[3][i];
  }
  *(bf16x8*)&dst[(2 * c4 + 0) * 512 + n * 8] = w0;
  *(bf16x8*)&dst[(2 * c4 + 1) * 512 + n * 8] = w1;
}

// V^T staging: v[0],v[1] = rows 2g,2g+1 ; v[2],v[3] = rows 2g+32,2g+33
static __device__ __forceinline__ void stage_V(__bf16* dst, int g, int n0,
                                               const f32x4* v) {
#pragma unroll
  for (int p = 0; p < 2; ++p) {
    const int k = 2 * g + 32 * p;
#pragma unroll
    for (int i = 0; i < 4; ++i) {
      bf16x2 pr;
      pr[0] = (__bf16)v[2 * p][i];
      pr[1] = (__bf16)v[2 * p + 1][i];
      *(bf16x2*)&dst[(n0 + i) * 68 + k] = pr;
    }
  }
}

__global__ __launch_bounds__(256, 2)
void General_Attention_62251255988379_kernel(const float* __restrict__ Q,
                                             const float* __restrict__ K,
                                             const float* __restrict__ V,
                                             float* __restrict__ out) {
  __shared__ __bf16 QsL[4096];
  __shared__ __bf16 KsL[2][4096];       // double-buffered K tile (frag layout)
  __shared__ __bf16 VtL[2][4352];       // double-buffered V^T [d][k], stride 68
  __shared__ __bf16 PtW[4 * 32 * 36];   // per-wave P slab [32 rows][36], stride 36
  __shared__ float  lsum[64];

  const int tid  = threadIdx.x;
  const int blk  = blockIdx.x;
  const int bb   = blk & 15;
  const int u    = blk >> 4;                       // heavy tiles dispatch first;
  const int rb   = (u < 16) ? (31 - u) : (u - 16); // CU pair (c,c+256) = const work
  const int row0 = rb * 64;
  const int lane = tid & 63;
  const int wave = tid >> 6;
  const int wr   = wave & 1;
  const int wc   = wave >> 1;
  const int ln   = lane & 31;
  const int half = lane >> 5;

  const float* Qb = Q + (size_t)bb * N_ * D_;
  const float* Kb = K + (size_t)bb * N_ * D_;
  const float* Vb = V + (size_t)bb * N_ * D_;
  float* Ob = out + (size_t)bb * N_ * D_;
  float* Ab = out + (size_t)B_ * N_ * D_ + (size_t)bb * N_ * N_;

  if (tid < 64) lsum[tid] = 0.0f;

  // ---- stage Q tile once, pre-scaled by 1/sqrt(D)=0.125 ----
  {
    const int m  = tid >> 2;
    const int c4 = tid & 3;
    const f32x4* src = (const f32x4*)(Qb + (size_t)(row0 + m) * D_ + c4 * 16);
    f32x4 f0 = src[0], f1 = src[1], f2 = src[2], f3 = src[3];
    bf16x8 w0, w1;
#pragma unroll
    for (int i = 0; i < 4; ++i) {
      w0[i]     = (__bf16)(f0[i] * 0.125f);
      w0[i + 4] = (__bf16)(f1[i] * 0.125f);
      w1[i]     = (__bf16)(f2[i] * 0.125f);
      w1[i + 4] = (__bf16)(f3[i] * 0.125f);
    }
    *(bf16x8*)&QsL[(2 * c4 + 0) * 512 + m * 8] = w0;
    *(bf16x8*)&QsL[(2 * c4 + 1) * 512 + m * 8] = w1;
  }
  __syncthreads();

  bf16x8 qf[4];
#pragma unroll
  for (int kk = 0; kk < 4; ++kk)
    qf[kk] = *(const bf16x8*)&QsL[(2 * kk + half) * 512 + (32 * wr + ln) * 8];

  const int n_st = tid >> 2;
  const int c4   = tid & 3;
  const float* Kst = Kb + (size_t)n_st * D_ + c4 * 16;

  // ===================== pass A: row sums of exp(s) =====================
  f32x4 kp[4];
  {
    const f32x4* kq = (const f32x4*)Kst;
    kp[0] = kq[0]; kp[1] = kq[1]; kp[2] = kq[2]; kp[3] = kq[3];
  }
  stage_K(KsL[0], n_st, c4, kp);

  float sums[16];
#pragma unroll
  for (int r = 0; r < 16; ++r) sums[r] = 0.0f;
  __syncthreads();

#pragma unroll 1
  for (int ct = 0; ct <= rb; ++ct) {
    const int cur = ct & 1;
    if (ct < rb) {  // prefetch next K tile into regs (overlaps compute)
      const f32x4* kq = (const f32x4*)(Kst + (size_t)(ct + 1) * 64 * D_);
      kp[0] = kq[0]; kp[1] = kq[1]; kp[2] = kq[2]; kp[3] = kq[3];
    }
    f32x16 s;
#pragma unroll
    for (int i = 0; i < 16; ++i) s[i] = 0.0f;
#pragma unroll
    for (int kk = 0; kk < 4; ++kk) {
      bf16x8 kf = *(const bf16x8*)&KsL[cur][(2 * kk + half) * 512 + (32 * wc + ln) * 8];
      s = __builtin_amdgcn_mfma_f32_32x32x16_bf16(qf[kk], kf, s, 0, 0, 0);
    }
    const bool diag = (ct == rb);
#pragma unroll
    for (int r = 0; r < 16; ++r) {
      float e = __expf(s[r]);
      if (diag) {
        const int ro = (r & 3) + 8 * (r >> 2) + 4 * half;
        e = ((32 * wc + ln) <= (32 * wr + ro)) ? e : 0.0f;
      }
      sums[r] += e;
    }
    if (ct < rb) stage_K(KsL[cur ^ 1], n_st, c4, kp);
    __syncthreads();
  }

  // butterfly-reduce across the 32 lanes holding each row's columns
#pragma unroll
  for (int r = 0; r < 16; ++r) {
    float v = sums[r];
    v += __shfl_xor(v, 1);
    v += __shfl_xor(v, 2);
    v += __shfl_xor(v, 4);
    v += __shfl_xor(v, 8);
    v += __shfl_xor(v, 16);
    sums[r] = v;
  }
  if (ln == 0) {
#pragma unroll
    for (int r = 0; r < 16; ++r) {
      const int ro = (r & 3) + 8 * (r >> 2) + 4 * half;
      atomicAdd(&lsum[32 * wr + ro], sums[r]);
    }
  }
  __syncthreads();

  float linv[16];
#pragma unroll
  for (int r = 0; r < 16; ++r) {
    const int ro = (r & 3) + 8 * (r >> 2) + 4 * half;
    linv[r] = 1.0f / lsum[32 * wr + ro];
  }

  // ===================== pass B: att writes + O = P.V =====================
  const int gV  = tid >> 4;
  const int n0v = (tid & 15) * 4;
  const float* Vst = Vb + (size_t)(2 * gV) * D_ + n0v;

  f32x4 vp[4];
  {
    const f32x4* kq = (const f32x4*)Kst;
    kp[0] = kq[0]; kp[1] = kq[1]; kp[2] = kq[2]; kp[3] = kq[3];
    vp[0] = *(const f32x4*)(Vst);
    vp[1] = *(const f32x4*)(Vst + D_);
    vp[2] = *(const f32x4*)(Vst + 32 * D_);
    vp[3] = *(const f32x4*)(Vst + 33 * D_);
  }
  stage_K(KsL[0], n_st, c4, kp);
  stage_V(VtL[0], gV, n0v, vp);

  f32x16 o0, o1;
#pragma unroll
  for (int i = 0; i < 16; ++i) { o0[i] = 0.0f; o1[i] = 0.0f; }
  __bf16* Pt = &PtW[wave * 32 * 36];
  __syncthreads();

#pragma unroll 1
  for (int ct = 0; ct <= rb; ++ct) {
    const int cur = ct & 1;
    const int c0  = ct * 64;
    if (ct < rb) {  // prefetch next K+V tiles into regs
      const size_t off = (size_t)(ct + 1) * 64 * D_;
      const f32x4* kq = (const f32x4*)(Kst + off);
      kp[0] = kq[0]; kp[1] = kq[1]; kp[2] = kq[2]; kp[3] = kq[3];
      vp[0] = *(const f32x4*)(Vst + off);
      vp[1] = *(const f32x4*)(Vst + off + D_);
      vp[2] = *(const f32x4*)(Vst + off + 32 * D_);
      vp[3] = *(const f32x4*)(Vst + off + 33 * D_);
    }
    // S = Q.K^T for this tile
    f32x16 s;
#pragma unroll
    for (int i = 0; i < 16; ++i) s[i] = 0.0f;
#pragma unroll
    for (int kk = 0; kk < 4; ++kk) {
      bf16x8 kf = *(const bf16x8*)&KsL[cur][(2 * kk + half) * 512 + (32 * wc + ln) * 8];
      s = __builtin_amdgcn_mfma_f32_32x32x16_bf16(qf[kk], kf, s, 0, 0, 0);
    }
    const bool diag = (ct == rb);
#pragma unroll
    for (int r = 0; r < 16; ++r) {
      const int ro = (r & 3) + 8 * (r >> 2) + 4 * half;
      float e = __expf(s[r]);
      if (diag) e = ((32 * wc + ln) <= (32 * wr + ro)) ? e : 0.0f;
      const float pv = e * linv[r];
      __builtin_nontemporal_store(pv,
          Ab + (size_t)(row0 + 32 * wr + ro) * N_ + c0 + 32 * wc + ln);
      Pt[ro * 36 + ln] = (__bf16)pv;   // wave-private: no barrier needed
    }
    // O partial: this wave's 32 columns only (k-range 32), cross-wave reduce later
#pragma unroll
    for (int kk2 = 0; kk2 < 2; ++kk2) {
      bf16x8 af = ld_frag(&Pt[ln * 36 + 16 * kk2 + 8 * half]);
      bf16x8 b0 = ld_frag(&VtL[cur][ln * 68 + 32 * wc + 16 * kk2 + 8 * half]);
      bf16x8 b1 = ld_frag(&VtL[cur][(32 + ln) * 68 + 32 * wc + 16 * kk2 + 8 * half]);
      o0 = __builtin_amdgcn_mfma_f32_32x32x16_bf16(af, b0, o0, 0, 0, 0);
      o1 = __builtin_amdgcn_mfma_f32_32x32x16_bf16(af, b1, o1, 0, 0, 0);
    }
    if (ct < rb) {
      stage_K(KsL[cur ^ 1], n_st, c4, kp);
      stage_V(VtL[cur ^ 1], gV, n0v, vp);
    }
    __syncthreads();
  }

  // ---- cross-wave O reduction (wc=1 partials -> wc=0) and store ----
  float* Ored = (float*)&KsL[0][0];  // 16 KB scratch, KsL dead now
  if (wc == 1) {
#pragma unroll
    for (int r = 0; r < 16; ++r) {
      const int ro = (r & 3) + 8 * (r >> 2) + 4 * half;
      Ored[(32 * wr + ro) * 64 + ln]      = o0[r];
      Ored[(32 * wr + ro) * 64 + 32 + ln] = o1[r];
    }
  }
  __syncthreads();
  if (wc == 0) {
#pragma unroll
    for (int r = 0; r < 16; ++r) {
      const int ro = (r & 3) + 8 * (r >> 2) + 4 * half;
      float* op = Ob + (size_t)(row0 + 32 * wr + ro) * D_;
      __builtin_nontemporal_store(o0[r] + Ored[(32 * wr + ro) * 64 + ln], op + ln);
      __builtin_nontemporal_store(o1[r] + Ored[(32 * wr + ro) * 64 + 32 + ln], op + 32 + ln);
    }
  }

  // ---- zero-fill strictly-upper columns of att for this row tile ----
  const int cz0 = 64 * (rb + 1);
  if (cz0 < N_) {
    f32x4 z = {0.0f, 0.0f, 0.0f, 0.0f};
#pragma unroll 1
    for (int rr = (tid >> 6); rr < 64; rr += 4) {
      float* rowp = Ab + (size_t)(row0 + rr) * N_;
      for (int x = cz0 + (tid & 63) * 4; x < N_; x += 256)
        __builtin_nontemporal_store(z, (f32x4*)(rowp + x));
    }
  }
}

extern "C" void kernel_launch(void* const* d_in, const int* in_sizes, int n_in,
                              void* d_out, int out_size, void* d_ws, size_t ws_size,
                              hipStream_t stream) {
  const float* Q = (const float*)d_in[0];
  const float* K = (const float*)d_in[1];
  const float* V = (const float*)d_in[2];
  (void)in_sizes; (void)n_in; (void)out_size; (void)d_ws; (void)ws_size;
  float* out = (float*)d_out;
  General_Attention_62251255988379_kernel<<<dim3(512), dim3(256), 0, stream>>>(Q, K, V, out);
}